// Round 1
// baseline (783.032 us; speedup 1.0000x reference)
//
#include <hip/hip_runtime.h>
#include <cstdint>
#include <cstddef>

#define NEG_SLOPE 0.2f
#define HEADS 4
#define CH 64
#define HC 256   // HEADS*CH

// ---- monotone int encoding of float for atomicMax ----
__device__ __forceinline__ int enc_f(float f) {
    int i = __float_as_int(f);
    return i >= 0 ? i : (i ^ 0x7FFFFFFF);
}
__device__ __forceinline__ float dec_f(int i) {
    return __int_as_float(i >= 0 ? i : (i ^ 0x7FFFFFFF));
}
__device__ __forceinline__ float leaky(float x) { return x > 0.f ? x : NEG_SLOPE * x; }

// ---------------- GEMM: C[N x 256] = A[N x K] * B[K x 256], fp32 ----------------
#define BM 64
#define BN 64
#define BK 16
__global__ void gemm_kernel(const float* __restrict__ A, const float* __restrict__ B,
                            float* __restrict__ C, int Nrows, int K) {
    __shared__ float As[BK][BM];
    __shared__ float Bs[BK][BN];
    const int bm = blockIdx.x * BM;
    const int bn = blockIdx.y * BN;
    const int t  = threadIdx.x;          // 256 threads
    const int tx = t & 15;               // N-dir
    const int ty = t >> 4;               // M-dir

    const int arow  = t >> 2;            // 0..63
    const int acol4 = (t & 3) * 4;       // 0,4,8,12
    const int brow  = t >> 4;            // 0..15
    const int bcol4 = (t & 15) * 4;

    float acc[4][4] = {};

    for (int k0 = 0; k0 < K; k0 += BK) {
        float4 av;
        const int gr = bm + arow;
        if (gr < Nrows) av = *(const float4*)(A + (size_t)gr * K + k0 + acol4);
        else            av = make_float4(0.f, 0.f, 0.f, 0.f);
        As[acol4 + 0][arow] = av.x;
        As[acol4 + 1][arow] = av.y;
        As[acol4 + 2][arow] = av.z;
        As[acol4 + 3][arow] = av.w;

        const float4 bv = *(const float4*)(B + (size_t)(k0 + brow) * 256 + bn + bcol4);
        *(float4*)&Bs[brow][bcol4] = bv;
        __syncthreads();

#pragma unroll
        for (int kk = 0; kk < BK; ++kk) {
            float a[4], b[4];
#pragma unroll
            for (int i = 0; i < 4; ++i) a[i] = As[kk][ty * 4 + i];
#pragma unroll
            for (int j = 0; j < 4; ++j) b[j] = Bs[kk][tx * 4 + j];
#pragma unroll
            for (int i = 0; i < 4; ++i)
#pragma unroll
                for (int j = 0; j < 4; ++j)
                    acc[i][j] += a[i] * b[j];
        }
        __syncthreads();
    }

#pragma unroll
    for (int i = 0; i < 4; ++i) {
        const int gr = bm + ty * 4 + i;
        if (gr < Nrows) {
            float4 v = make_float4(acc[i][0], acc[i][1], acc[i][2], acc[i][3]);
            *(float4*)(C + (size_t)gr * 256 + bn + tx * 4) = v;
        }
    }
}

// ---- per-node: alpha_s, alpha_d, and init running max with self-loop logit ----
__global__ void alpha_kernel(const float* __restrict__ h, const float* __restrict__ a_src,
                             const float* __restrict__ a_dst,
                             float* __restrict__ alpha_s, float* __restrict__ alpha_d,
                             int* __restrict__ m_int, int Nn) {
    const int n = blockIdx.x;
    if (n >= Nn) return;
    const int t = threadIdx.x;           // 256 = 4 heads x 64 ch
    const int hd = t >> 6, lane = t & 63;
    const float v = h[(size_t)n * HC + t];
    float s = v * a_src[t];
    float d = v * a_dst[t];
#pragma unroll
    for (int off = 32; off; off >>= 1) {
        s += __shfl_down(s, off);
        d += __shfl_down(d, off);
    }
    if (lane == 0) {
        alpha_s[n * HEADS + hd] = s;
        alpha_d[n * HEADS + hd] = d;
        m_int[n * HEADS + hd] = enc_f(leaky(s + d));   // self-loop participates in max
    }
}

// ---- edge pass A: segment max over dst ----
__global__ void edge_max_kernel(const int* __restrict__ ei,
                                const float* __restrict__ alpha_s, const float* __restrict__ alpha_d,
                                int* __restrict__ m_int, int E) {
    const int t = blockIdx.x * blockDim.x + threadIdx.x;
    if (t >= E * HEADS) return;
    const int e = t >> 2, hd = t & 3;
    const int src = ei[e], dst = ei[E + e];
    const float ev = leaky(alpha_s[src * HEADS + hd] + alpha_d[dst * HEADS + hd]);
    atomicMax(&m_int[dst * HEADS + hd], enc_f(ev));
}

// ---- per-node: init denom with self-loop weight ----
__global__ void denom_init_kernel(const float* __restrict__ alpha_s, const float* __restrict__ alpha_d,
                                  const int* __restrict__ m_int, float* __restrict__ denom, int Nn) {
    const int t = blockIdx.x * blockDim.x + threadIdx.x;
    if (t >= Nn * HEADS) return;
    const float ev = leaky(alpha_s[t] + alpha_d[t]);
    denom[t] = __expf(ev - dec_f(m_int[t]));
}

// ---- edge pass B: denominator sum ----
__global__ void edge_sum_kernel(const int* __restrict__ ei,
                                const float* __restrict__ alpha_s, const float* __restrict__ alpha_d,
                                const int* __restrict__ m_int, float* __restrict__ denom, int E) {
    const int t = blockIdx.x * blockDim.x + threadIdx.x;
    if (t >= E * HEADS) return;
    const int e = t >> 2, hd = t & 3;
    const int src = ei[e], dst = ei[E + e];
    const float ev = leaky(alpha_s[src * HEADS + hd] + alpha_d[dst * HEADS + hd]);
    const float w = __expf(ev - dec_f(m_int[dst * HEADS + hd]));
    atomicAdd(&denom[dst * HEADS + hd], w);
}

// ---- edge pass C: weighted aggregation, head-mean folded (1/H), one wave per edge ----
__global__ void edge_agg_kernel(const int* __restrict__ ei,
                                const float* __restrict__ alpha_s, const float* __restrict__ alpha_d,
                                const int* __restrict__ m_int, const float* __restrict__ denom,
                                const float* __restrict__ hbuf, float* __restrict__ agg, int E) {
    const int wid = (blockIdx.x * blockDim.x + threadIdx.x) >> 6;
    const int lane = threadIdx.x & 63;
    if (wid >= E) return;
    const int src = ei[wid], dst = ei[E + wid];
    float acc = 0.f;
#pragma unroll
    for (int hd = 0; hd < HEADS; ++hd) {
        const float ev = leaky(alpha_s[src * HEADS + hd] + alpha_d[dst * HEADS + hd]);
        const float w  = __expf(ev - dec_f(m_int[dst * HEADS + hd]));
        const float al = w / (denom[dst * HEADS + hd] + 1e-16f);
        acc += al * hbuf[(size_t)src * HC + hd * CH + lane];
    }
    atomicAdd(&agg[(size_t)dst * CH + lane], 0.25f * acc);
}

// ---- per-node finalize: add self-loop msg, bias, optional ELU ----
__global__ void finalize_kernel(const float* __restrict__ hbuf,
                                const float* __restrict__ alpha_s, const float* __restrict__ alpha_d,
                                const int* __restrict__ m_int, const float* __restrict__ denom,
                                const float* __restrict__ bias,
                                const float* __restrict__ agg, float* __restrict__ outp,
                                int Nn, int do_elu) {
    const size_t t = (size_t)blockIdx.x * blockDim.x + threadIdx.x;
    if (t >= (size_t)Nn * CH) return;
    const int n = (int)(t >> 6), c = (int)(t & 63);
    float acc = agg[t];
#pragma unroll
    for (int hd = 0; hd < HEADS; ++hd) {
        const float ev = leaky(alpha_s[n * HEADS + hd] + alpha_d[n * HEADS + hd]);
        const float w  = __expf(ev - dec_f(m_int[n * HEADS + hd]));
        const float al = w / (denom[n * HEADS + hd] + 1e-16f);
        acc += 0.25f * al * hbuf[(size_t)n * HC + hd * CH + c];
    }
    float val = acc + bias[c];
    if (do_elu) val = val > 0.f ? val : expm1f(val);
    outp[t] = val;
}

// ------------------------------------------------------------------
extern "C" void kernel_launch(void* const* d_in, const int* in_sizes, int n_in,
                              void* d_out, int out_size, void* d_ws, size_t ws_size,
                              hipStream_t stream) {
    const float* x   = (const float*)d_in[0];
    const int*   ei  = (const int*)d_in[1];
    const float* W1  = (const float*)d_in[2];
    const float* a1s = (const float*)d_in[3];
    const float* a1d = (const float*)d_in[4];
    const float* b1  = (const float*)d_in[5];
    const float* W2  = (const float*)d_in[6];
    const float* a2s = (const float*)d_in[7];
    const float* a2d = (const float*)d_in[8];
    const float* b2  = (const float*)d_in[9];

    const int N = in_sizes[0] / HC;   // 50000
    const int E = in_sizes[1] / 2;    // 800000

    char* ws = (char*)d_ws;
    float* hbuf  = (float*)ws;                                     // N*256 f32
    float* agg   = (float*)(ws + (size_t)N * HC * 4);              // N*64 f32 (also holds out1)
    float* alps  = (float*)(ws + (size_t)N * HC * 4 + (size_t)N * CH * 4);
    float* alpd  = alps + (size_t)N * HEADS;
    int*   mint  = (int*)(alpd + (size_t)N * HEADS);
    float* denom = (float*)(mint + (size_t)N * HEADS);
    float* outp  = (float*)d_out;

    const int edge_blk = (E * HEADS + 255) / 256;
    const int node4_blk = (N * HEADS + 255) / 256;
    const int node64_blk = (N * CH + 255) / 256;
    const int agg_blk = (E + 3) / 4;               // 4 waves/block, wave per edge
    const dim3 gemm_grid((N + BM - 1) / BM, HC / BN);

    // ---------------- layer 1 ----------------
    hipMemsetAsync(agg, 0, (size_t)N * CH * sizeof(float), stream);
    gemm_kernel<<<gemm_grid, 256, 0, stream>>>(x, W1, hbuf, N, 256);
    alpha_kernel<<<N, 256, 0, stream>>>(hbuf, a1s, a1d, alps, alpd, mint, N);
    edge_max_kernel<<<edge_blk, 256, 0, stream>>>(ei, alps, alpd, mint, E);
    denom_init_kernel<<<node4_blk, 256, 0, stream>>>(alps, alpd, mint, denom, N);
    edge_sum_kernel<<<edge_blk, 256, 0, stream>>>(ei, alps, alpd, mint, denom, E);
    edge_agg_kernel<<<agg_blk, 256, 0, stream>>>(ei, alps, alpd, mint, denom, hbuf, agg, E);
    finalize_kernel<<<node64_blk, 256, 0, stream>>>(hbuf, alps, alpd, mint, denom, b1,
                                                    agg, agg, N, 1);   // in-place -> out1

    // ---------------- layer 2 ----------------
    gemm_kernel<<<gemm_grid, 256, 0, stream>>>(agg, W2, hbuf, N, 64);
    hipMemsetAsync(agg, 0, (size_t)N * CH * sizeof(float), stream);
    alpha_kernel<<<N, 256, 0, stream>>>(hbuf, a2s, a2d, alps, alpd, mint, N);
    edge_max_kernel<<<edge_blk, 256, 0, stream>>>(ei, alps, alpd, mint, E);
    denom_init_kernel<<<node4_blk, 256, 0, stream>>>(alps, alpd, mint, denom, N);
    edge_sum_kernel<<<edge_blk, 256, 0, stream>>>(ei, alps, alpd, mint, denom, E);
    edge_agg_kernel<<<agg_blk, 256, 0, stream>>>(ei, alps, alpd, mint, denom, hbuf, agg, E);
    finalize_kernel<<<node64_blk, 256, 0, stream>>>(hbuf, alps, alpd, mint, denom, b2,
                                                    agg, outp, N, 0);
}